// Round 4
// baseline (185.905 us; speedup 1.0000x reference)
//
#include <hip/hip_runtime.h>

// XConv bf16-MFMA pipeline. N=16, P=1024, K=16, D=3, Cf=64, Fin=64,
// Ccat=128, DM=4, Cout=128. NPTS=16384 points, 262144 rows.
//
// MFMA conventions (mfma_f32_16x16x32_bf16, m89-verified):
//  A-frag: lane&15 = M-row, k = (lane>>4)*8 + [0..7]  (8 contiguous bf16, [M][K] row-major)
//  B-frag: lane&15 = N-col, k = (lane>>4)*8 + [0..7]  ([N][K] row-major)
//  D:      col(N) = lane&15, row(M) = (lane>>4)*4 + reg

#define NPTS 16384

typedef short  s16x8 __attribute__((ext_vector_type(8)));
typedef float  f32x4 __attribute__((ext_vector_type(4)));

__device__ inline unsigned short f2b(float f) {
    unsigned u = __builtin_bit_cast(unsigned, f);
    unsigned r = u + 0x7FFF + ((u >> 16) & 1);
    return (unsigned short)(r >> 16);
}

#define MFMA(a,b,c) __builtin_amdgcn_mfma_f32_16x16x32_bf16((a),(b),(c),0,0,0)

// ---------------- kW: convert weights to bf16 (B^T layouts) ----------------
__global__ __launch_bounds__(256) void kW_cvt(
    const float* __restrict__ Wxc, const float* __restrict__ Wx1,
    const float* __restrict__ Wx2, const float* __restrict__ Wf2,
    const float* __restrict__ Wpw, unsigned short* __restrict__ Wb)
{
    unsigned short* Wxcb = Wb;            // [256][64] (K 48->64 zero-pad)
    unsigned short* Wx1b = Wxcb + 16384;  // [256][256]
    unsigned short* Wx2b = Wx1b + 65536;  // [256][256]
    unsigned short* Wf2b = Wx2b + 65536;  // [64][64]
    unsigned short* Wpwb = Wf2b + 4096;   // [128][512]
    int idx = blockIdx.x * 256 + threadIdx.x;
    if (idx < 16384) { int o = idx >> 6, j = idx & 63;
        Wxcb[idx] = (j < 48) ? f2b(Wxc[o*48 + j]) : 0; return; }
    idx -= 16384;
    if (idx < 65536) { Wx1b[idx] = f2b(Wx1[idx]); return; }
    idx -= 65536;
    if (idx < 65536) { Wx2b[idx] = f2b(Wx2[idx]); return; }
    idx -= 65536;
    if (idx < 4096)  { Wf2b[idx] = f2b(Wf2[idx]); return; }
    idx -= 4096;
    if (idx < 65536) { Wpwb[idx] = f2b(Wpw[idx]); return; }
}

// ---------------- kA: X-chain as 3 chained MFMA GEMMs ----------------
// 16 points/block, 256 thr = 4 waves; wave w owns output cols 64w..64w+63.
#define SA 72     // ptsl stride (bf16)
#define SX 264    // X1s/X2s stride
__global__ __launch_bounds__(256) void kA_mfma(
    const float* __restrict__ rep, const float* __restrict__ pts,
    const unsigned short* __restrict__ Wxcb, const float* __restrict__ bxc,
    const unsigned short* __restrict__ Wx1b, const float* __restrict__ bx1,
    const unsigned short* __restrict__ Wx2b, const float* __restrict__ bx2,
    unsigned short* __restrict__ X3b)
{
    __shared__ __align__(16) unsigned short pA[16*SA];
    __shared__ __align__(16) unsigned short X1s[16*SX];
    __shared__ __align__(16) unsigned short X2s[16*SX];
    const int tid = threadIdx.x;
    const int w = tid >> 6, lane = tid & 63, cl = lane & 15, lg = lane >> 4;
    const int base = blockIdx.x * 16;

    for (int idx = tid; idx < 1024; idx += 256) {     // stage local coords
        int pt = idx >> 6, j = idx & 63;
        float v = 0.f;
        if (j < 48) { int d = j >> 4, kk = j & 15;
            v = pts[(size_t)((base+pt)*16 + kk)*3 + d] - rep[(base+pt)*3 + d]; }
        pA[pt*SA + j] = f2b(v);
    }
    __syncthreads();

    f32x4 z = {0.f,0.f,0.f,0.f};
    {   // phase 1: X1 = relu(ptsl @ Wxc^T + b), K=48(->64)
        f32x4 acc[4] = {z,z,z,z};
        #pragma unroll
        for (int ks = 0; ks < 2; ++ks) {
            s16x8 a = *(const s16x8*)&pA[cl*SA + ks*32 + lg*8];
            #pragma unroll
            for (int ct = 0; ct < 4; ++ct) {
                int o = w*64 + ct*16 + cl;
                s16x8 b = *(const s16x8*)&Wxcb[o*64 + ks*32 + lg*8];
                acc[ct] = MFMA(a, b, acc[ct]);
            }
        }
        #pragma unroll
        for (int ct = 0; ct < 4; ++ct) {
            int o = w*64 + ct*16 + cl;
            float bias = bxc[o];
            #pragma unroll
            for (int r = 0; r < 4; ++r)
                X1s[(lg*4 + r)*SX + o] = f2b(fmaxf(acc[ct][r] + bias, 0.f));
        }
    }
    __syncthreads();

    {   // phase 2: X2 = relu(X1 @ Wx1^T + b), K=256
        f32x4 acc[4] = {z,z,z,z};
        #pragma unroll
        for (int ks = 0; ks < 8; ++ks) {
            s16x8 a = *(const s16x8*)&X1s[cl*SX + ks*32 + lg*8];
            #pragma unroll
            for (int ct = 0; ct < 4; ++ct) {
                int o = w*64 + ct*16 + cl;
                s16x8 b = *(const s16x8*)&Wx1b[(size_t)o*256 + ks*32 + lg*8];
                acc[ct] = MFMA(a, b, acc[ct]);
            }
        }
        #pragma unroll
        for (int ct = 0; ct < 4; ++ct) {
            int o = w*64 + ct*16 + cl;
            float bias = bx1[o];
            #pragma unroll
            for (int r = 0; r < 4; ++r)
                X2s[(lg*4 + r)*SX + o] = f2b(fmaxf(acc[ct][r] + bias, 0.f));
        }
    }
    __syncthreads();

    {   // phase 3: X3 = X2 @ Wx2^T + b (linear) -> global bf16 [p][256]
        f32x4 acc[4] = {z,z,z,z};
        #pragma unroll
        for (int ks = 0; ks < 8; ++ks) {
            s16x8 a = *(const s16x8*)&X2s[cl*SX + ks*32 + lg*8];
            #pragma unroll
            for (int ct = 0; ct < 4; ++ct) {
                int o = w*64 + ct*16 + cl;
                s16x8 b = *(const s16x8*)&Wx2b[(size_t)o*256 + ks*32 + lg*8];
                acc[ct] = MFMA(a, b, acc[ct]);
            }
        }
        #pragma unroll
        for (int ct = 0; ct < 4; ++ct) {
            int o = w*64 + ct*16 + cl;
            float bias = bx2[o];
            #pragma unroll
            for (int r = 0; r < 4; ++r)
                X3b[(size_t)(base + lg*4 + r)*256 + o] = f2b(acc[ct][r] + bias);
        }
    }
}

// ---------------- kB v2: lift + fts_X + depthwise (clean banking) ----------------
// 4 points/block (64 rows), 256 thr = 4 waves; wave w owns point w.
// fcT[c][local row] c=0..63 lifted (written transposed by swapped FC2 MFMA),
// c=64..127 fts (staged transposed). Strides 72 shorts (16B-aligned frags).
#define SH 72
#define SF 72
__global__ __launch_bounds__(256) void kB_mfma(
    const float* __restrict__ rep, const float* __restrict__ pts,
    const float* __restrict__ fts,
    const float* __restrict__ Wf1, const float* __restrict__ bf1,
    const unsigned short* __restrict__ Wf2b, const float* __restrict__ bf2,
    const float* __restrict__ Wdw, const float* __restrict__ bdw,
    const unsigned short* __restrict__ X3b, unsigned short* __restrict__ dwb)
{
    __shared__ __align__(16) unsigned short hs[64*SH];     // h[row][f]
    __shared__ __align__(16) unsigned short fcT[128*SF];   // fcat^T[c][row]
    const int tid = threadIdx.x;
    const int w = tid >> 6, lane = tid & 63, cl = lane & 15, lg = lane >> 4;
    const int pbase = blockIdx.x * 4, rbase = pbase * 16;

    // ---- early global loads (latency hides under FC1) ----
    float2 fv[8];
    const int fc0 = (tid & 31) * 2;       // fts column pair
    const int fr0 = tid >> 5;             // row (+ it*8)
    #pragma unroll
    for (int it = 0; it < 8; ++it)
        fv[it] = *(const float2*)&fts[(size_t)(rbase + fr0 + it*8)*64 + fc0];

    s16x8 xa = {0,0,0,0,0,0,0,0};         // X A-frag, K 16->32 zero-pad
    if (lg < 2) xa = *(const s16x8*)&X3b[(size_t)(pbase + w)*256 + cl*16 + lg*8];

    // ---- FC1 (VALU, K=3) -> hs[row][f] ----
    {
        const int r2 = tid >> 2, fg = tid & 3;
        const int row = rbase + r2, q = row >> 4;
        float x0 = pts[(size_t)row*3+0] - rep[q*3+0];
        float x1 = pts[(size_t)row*3+1] - rep[q*3+1];
        float x2 = pts[(size_t)row*3+2] - rep[q*3+2];
        #pragma unroll
        for (int k4 = 0; k4 < 4; ++k4) {
            unsigned short hv[4];
            #pragma unroll
            for (int j = 0; j < 4; ++j) {
                int f = fg*16 + k4*4 + j;
                float h = fmaxf(bf1[f] + Wf1[f*3]*x0 + Wf1[f*3+1]*x1 + Wf1[f*3+2]*x2, 0.f);
                hv[j] = f2b(h);
            }
            ushort4 pk; pk.x=hv[0]; pk.y=hv[1]; pk.z=hv[2]; pk.w=hv[3];
            *(ushort4*)&hs[r2*SH + fg*16 + k4*4] = pk;
        }
    }
    // ---- fts -> fcT[64+c][row] (transposed scalar writes, spread banks) ----
    #pragma unroll
    for (int it = 0; it < 8; ++it) {
        int r = fr0 + it*8;
        fcT[(64 + fc0    )*SF + r] = f2b(fv[it].x);
        fcT[(64 + fc0 + 1)*SF + r] = f2b(fv[it].y);
    }
    __syncthreads();

    f32x4 z = {0.f,0.f,0.f,0.f};
    // ---- FC2 swapped MFMA: D[g][row] = sum_f Wf2[g][f] h[row][f] ----
    {
        f32x4 acc[4] = {z,z,z,z};
        #pragma unroll
        for (int ks = 0; ks < 2; ++ks) {
            s16x8 b = *(const s16x8*)&hs[(w*16 + cl)*SH + ks*32 + lg*8];
            #pragma unroll
            for (int gt = 0; gt < 4; ++gt) {
                s16x8 a = *(const s16x8*)&Wf2b[(gt*16 + cl)*64 + ks*32 + lg*8];
                acc[gt] = MFMA(a, b, acc[gt]);
            }
        }
        #pragma unroll
        for (int gt = 0; gt < 4; ++gt) {
            #pragma unroll
            for (int rr = 0; rr < 4; ++rr) {
                int g = gt*16 + lg*4 + rr;
                fcT[g*SF + w*16 + cl] = f2b(fmaxf(acc[gt][rr] + bf2[g], 0.f));
            }
        }
    }
    __syncthreads();

    // ---- fts_X: fx[ct] = X_p @ fcat  (D rows i=lg*4+r, cols c=ct*16+cl) ----
    f32x4 fx[8];
    #pragma unroll
    for (int ct = 0; ct < 8; ++ct) {
        int c = ct*16 + cl;
        s16x8 b = *(const s16x8*)&fcT[c*SF + w*16 + (lg & 1)*8];
        fx[ct] = MFMA(xa, b, z);
    }

    // ---- depthwise + bias -> dwb bf16 [p][512] ----
    #pragma unroll
    for (int ct = 0; ct < 8; ++ct) {
        int c = ct*16 + cl;
        float om[4];
        #pragma unroll
        for (int m = 0; m < 4; ++m) {
            float4 wv = *(const float4*)&Wdw[(size_t)(c*4 + m)*16 + lg*4];
            float s = fx[ct][0]*wv.x + fx[ct][1]*wv.y + fx[ct][2]*wv.z + fx[ct][3]*wv.w;
            s += __shfl_xor(s, 16);
            s += __shfl_xor(s, 32);
            om[m] = s + bdw[c*4 + m];
        }
        if (lg == 0) {
            ushort4 pk; pk.x = f2b(om[0]); pk.y = f2b(om[1]); pk.z = f2b(om[2]); pk.w = f2b(om[3]);
            *(ushort4*)&dwb[(size_t)(pbase + w)*512 + c*4] = pk;
        }
    }
}

// ---------------- kC: pointwise MFMA GEMM (M=16384, N=128, K=512) ----------------
__global__ __launch_bounds__(256) void kC_mfma(
    const unsigned short* __restrict__ dwb, const unsigned short* __restrict__ Wpwb,
    const float* __restrict__ bpw, float* __restrict__ y)
{
    const int tid = threadIdx.x;
    const int w = tid >> 6, lane = tid & 63, cl = lane & 15, lg = lane >> 4;
    const int m0 = blockIdx.x*32 + (w & 1)*16;
    const int nh = w >> 1;
    f32x4 z = {0.f,0.f,0.f,0.f};
    f32x4 acc[4] = {z,z,z,z};
    for (int ks = 0; ks < 16; ++ks) {
        s16x8 a = *(const s16x8*)&dwb[(size_t)(m0 + cl)*512 + ks*32 + lg*8];
        #pragma unroll
        for (int ct = 0; ct < 4; ++ct) {
            int o = nh*64 + ct*16 + cl;
            s16x8 b = *(const s16x8*)&Wpwb[(size_t)o*512 + ks*32 + lg*8];
            acc[ct] = MFMA(a, b, acc[ct]);
        }
    }
    #pragma unroll
    for (int ct = 0; ct < 4; ++ct) {
        int o = nh*64 + ct*16 + cl;
        float bias = bpw[o];
        #pragma unroll
        for (int r = 0; r < 4; ++r)
            y[(size_t)(m0 + lg*4 + r)*128 + o] = acc[ct][r] + bias;
    }
}

// ---------------- kZ / kD1 / kD2 / kE: BN + relu ----------------
__global__ void kZ_zero(float* __restrict__ acc) { acc[threadIdx.x] = 0.f; }

__global__ __launch_bounds__(256) void kD1_part(
    const float* __restrict__ y, float* __restrict__ accS, float* __restrict__ accS2)
{
    __shared__ float sL[8][128], s2L[8][128];
    const int tid = threadIdx.x;
    const int rg = tid >> 5, clx = tid & 31;
    const int base = blockIdx.x * 64;
    float4 s = make_float4(0,0,0,0), s2 = make_float4(0,0,0,0);
    #pragma unroll
    for (int rr = 0; rr < 8; ++rr) {
        float4 v = *(const float4*)(y + (size_t)(base + rg*8 + rr)*128 + clx*4);
        s.x += v.x; s.y += v.y; s.z += v.z; s.w += v.w;
        s2.x += v.x*v.x; s2.y += v.y*v.y; s2.z += v.z*v.z; s2.w += v.w*v.w;
    }
    *(float4*)&sL[rg][clx*4] = s;
    *(float4*)&s2L[rg][clx*4] = s2;
    __syncthreads();
    if (tid < 128) {
        float a = 0.f, b = 0.f;
        #pragma unroll
        for (int g = 0; g < 8; ++g) { a += sL[g][tid]; b += s2L[g][tid]; }
        atomicAdd(accS + tid, a);
        atomicAdd(accS2 + tid, b);
    }
}

__global__ void kD2_fin(
    const float* __restrict__ accS, const float* __restrict__ accS2,
    const float* __restrict__ gamma, const float* __restrict__ beta,
    float* __restrict__ st)
{
    const int c = threadIdx.x;
    float mean = accS[c] * (1.f/NPTS);
    float var  = accS2[c] * (1.f/NPTS) - mean*mean;
    float rstd = rsqrtf(var + 1e-5f);
    float sc = gamma[c] * rstd;
    st[c] = sc;
    st[128 + c] = beta[c] - mean*sc;
}

__global__ __launch_bounds__(256) void kE_final(
    const float* __restrict__ y, const float* __restrict__ st,
    float* __restrict__ out)
{
    const int idx = blockIdx.x*256 + threadIdx.x;
    float4 v = ((const float4*)y)[idx];
    int o0 = (idx & 31) << 2;
    float4 sc = *(const float4*)(st + o0);
    float4 sh = *(const float4*)(st + 128 + o0);
    float4 r;
    r.x = fmaxf(v.x*sc.x + sh.x, 0.f);
    r.y = fmaxf(v.y*sc.y + sh.y, 0.f);
    r.z = fmaxf(v.z*sc.z + sh.z, 0.f);
    r.w = fmaxf(v.w*sc.w + sh.w, 0.f);
    ((float4*)out)[idx] = r;
}

extern "C" void kernel_launch(void* const* d_in, const int* in_sizes, int n_in,
                              void* d_out, int out_size, void* d_ws, size_t ws_size,
                              hipStream_t stream) {
    const float* rep  = (const float*)d_in[0];
    const float* pts  = (const float*)d_in[1];
    const float* fts  = (const float*)d_in[2];
    const float* Wf1  = (const float*)d_in[3];
    const float* bf1  = (const float*)d_in[4];
    const float* Wf2  = (const float*)d_in[5];
    const float* bf2  = (const float*)d_in[6];
    const float* Wxc  = (const float*)d_in[7];
    const float* bxc  = (const float*)d_in[8];
    const float* Wx1  = (const float*)d_in[9];
    const float* bx1  = (const float*)d_in[10];
    const float* Wx2  = (const float*)d_in[11];
    const float* bx2  = (const float*)d_in[12];
    const float* Wdw  = (const float*)d_in[13];
    const float* bdw  = (const float*)d_in[14];
    const float* Wpw  = (const float*)d_in[15];
    const float* bpw  = (const float*)d_in[16];
    const float* gam  = (const float*)d_in[17];
    const float* bet  = (const float*)d_in[18];

    unsigned short* X3b = (unsigned short*)d_ws;                 // 16384*256 bf16
    unsigned short* dwb = X3b + (size_t)NPTS*256;                // 16384*512 bf16
    float* y   = (float*)(dwb + (size_t)NPTS*512);               // 16384*128 f32
    float* st  = y + (size_t)NPTS*128;                           // 256
    float* acc = st + 256;                                       // 256
    unsigned short* Wb = (unsigned short*)(acc + 256);           // 217088 bf16
    unsigned short* Wxcb = Wb;
    unsigned short* Wx1b = Wxcb + 16384;
    unsigned short* Wx2b = Wx1b + 65536;
    unsigned short* Wf2b = Wx2b + 65536;
    unsigned short* Wpwb = Wf2b + 4096;

    kZ_zero<<<1, 256, 0, stream>>>(acc);
    kW_cvt<<<848, 256, 0, stream>>>(Wxc, Wx1, Wx2, Wf2, Wpw, Wb);
    kA_mfma<<<NPTS/16, 256, 0, stream>>>(rep, pts, Wxcb, bxc, Wx1b, bx1, Wx2b, bx2, X3b);
    kB_mfma<<<NPTS/4, 256, 0, stream>>>(rep, pts, fts, Wf1, bf1, Wf2b, bf2, Wdw, bdw, X3b, dwb);
    kC_mfma<<<NPTS/32, 256, 0, stream>>>(dwb, Wpwb, bpw, y);
    kD1_part<<<NPTS/64, 256, 0, stream>>>(y, acc, acc + 128);
    kD2_fin<<<1, 128, 0, stream>>>(acc, acc + 128, gam, bet, st);
    kE_final<<<(NPTS*128/4)/256, 256, 0, stream>>>(y, st, (float*)d_out);
}

// Round 5
// 172.984 us; speedup vs baseline: 1.0747x; 1.0747x over previous
//
#include <hip/hip_runtime.h>

// XConv bf16-MFMA pipeline. N=16, P=1024, K=16, D=3, Cf=64, Fin=64,
// Ccat=128, DM=4, Cout=128. NPTS=16384 points, 262144 rows.
//
// MFMA conventions (mfma_f32_16x16x32_bf16, m89-verified):
//  A-frag: lane&15 = M-row, k = (lane>>4)*8 + [0..7]  (8 contiguous bf16, [M][K] row-major)
//  B-frag: lane&15 = N-col, k = (lane>>4)*8 + [0..7]  ([N][K] row-major)
//  D:      col(N) = lane&15, row(M) = (lane>>4)*4 + reg

#define NPTS 16384

typedef short  s16x8 __attribute__((ext_vector_type(8)));
typedef float  f32x4 __attribute__((ext_vector_type(4)));

__device__ inline unsigned short f2b(float f) {
    unsigned u = __builtin_bit_cast(unsigned, f);
    unsigned r = u + 0x7FFF + ((u >> 16) & 1);
    return (unsigned short)(r >> 16);
}

#define MFMA(a,b,c) __builtin_amdgcn_mfma_f32_16x16x32_bf16((a),(b),(c),0,0,0)

// ---------------- kW: convert weights to bf16 (B^T layouts) + W1 pack ----------------
__global__ __launch_bounds__(256) void kW_cvt(
    const float* __restrict__ Wxc, const float* __restrict__ Wx1,
    const float* __restrict__ Wx2, const float* __restrict__ Wf2,
    const float* __restrict__ Wpw, const float* __restrict__ Wf1,
    const float* __restrict__ bf1, unsigned short* __restrict__ Wb,
    float* __restrict__ W1p)
{
    unsigned short* Wxcb = Wb;            // [256][64] (K 48->64 zero-pad)
    unsigned short* Wx1b = Wxcb + 16384;  // [256][256]
    unsigned short* Wx2b = Wx1b + 65536;  // [256][256]
    unsigned short* Wf2b = Wx2b + 65536;  // [64][64]
    unsigned short* Wpwb = Wf2b + 4096;   // [128][512]
    int idx = blockIdx.x * 256 + threadIdx.x;
    if (idx < 16384) { int o = idx >> 6, j = idx & 63;
        Wxcb[idx] = (j < 48) ? f2b(Wxc[o*48 + j]) : 0; return; }
    idx -= 16384;
    if (idx < 65536) { Wx1b[idx] = f2b(Wx1[idx]); return; }
    idx -= 65536;
    if (idx < 65536) { Wx2b[idx] = f2b(Wx2[idx]); return; }
    idx -= 65536;
    if (idx < 4096)  { Wf2b[idx] = f2b(Wf2[idx]); return; }
    idx -= 4096;
    if (idx < 65536) { Wpwb[idx] = f2b(Wpw[idx]); return; }
    idx -= 65536;
    if (idx < 256)   { int f = idx >> 2, j = idx & 3;
        W1p[idx] = (j < 3) ? Wf1[f*3 + j] : bf1[f]; return; }
}

// ---------------- kA: X-chain as 3 chained MFMA GEMMs ----------------
// 16 points/block, 256 thr = 4 waves; wave w owns output cols 64w..64w+63.
#define SA 72     // ptsl stride (bf16)
#define SX 264    // X1s/X2s stride
__global__ __launch_bounds__(256) void kA_mfma(
    const float* __restrict__ rep, const float* __restrict__ pts,
    const unsigned short* __restrict__ Wxcb, const float* __restrict__ bxc,
    const unsigned short* __restrict__ Wx1b, const float* __restrict__ bx1,
    const unsigned short* __restrict__ Wx2b, const float* __restrict__ bx2,
    unsigned short* __restrict__ X3b)
{
    __shared__ __align__(16) unsigned short pA[16*SA];
    __shared__ __align__(16) unsigned short X1s[16*SX];
    __shared__ __align__(16) unsigned short X2s[16*SX];
    const int tid = threadIdx.x;
    const int w = tid >> 6, lane = tid & 63, cl = lane & 15, lg = lane >> 4;
    const int base = blockIdx.x * 16;

    for (int idx = tid; idx < 1024; idx += 256) {     // stage local coords
        int pt = idx >> 6, j = idx & 63;
        float v = 0.f;
        if (j < 48) { int d = j >> 4, kk = j & 15;
            v = pts[(size_t)((base+pt)*16 + kk)*3 + d] - rep[(base+pt)*3 + d]; }
        pA[pt*SA + j] = f2b(v);
    }
    __syncthreads();

    f32x4 z = {0.f,0.f,0.f,0.f};
    {   // phase 1: X1 = relu(ptsl @ Wxc^T + b), K=48(->64)
        f32x4 acc[4] = {z,z,z,z};
        #pragma unroll
        for (int ks = 0; ks < 2; ++ks) {
            s16x8 a = *(const s16x8*)&pA[cl*SA + ks*32 + lg*8];
            #pragma unroll
            for (int ct = 0; ct < 4; ++ct) {
                int o = w*64 + ct*16 + cl;
                s16x8 b = *(const s16x8*)&Wxcb[o*64 + ks*32 + lg*8];
                acc[ct] = MFMA(a, b, acc[ct]);
            }
        }
        #pragma unroll
        for (int ct = 0; ct < 4; ++ct) {
            int o = w*64 + ct*16 + cl;
            float bias = bxc[o];
            #pragma unroll
            for (int r = 0; r < 4; ++r)
                X1s[(lg*4 + r)*SX + o] = f2b(fmaxf(acc[ct][r] + bias, 0.f));
        }
    }
    __syncthreads();

    {   // phase 2: X2 = relu(X1 @ Wx1^T + b), K=256
        f32x4 acc[4] = {z,z,z,z};
        #pragma unroll
        for (int ks = 0; ks < 8; ++ks) {
            s16x8 a = *(const s16x8*)&X1s[cl*SX + ks*32 + lg*8];
            #pragma unroll
            for (int ct = 0; ct < 4; ++ct) {
                int o = w*64 + ct*16 + cl;
                s16x8 b = *(const s16x8*)&Wx1b[(size_t)o*256 + ks*32 + lg*8];
                acc[ct] = MFMA(a, b, acc[ct]);
            }
        }
        #pragma unroll
        for (int ct = 0; ct < 4; ++ct) {
            int o = w*64 + ct*16 + cl;
            float bias = bx1[o];
            #pragma unroll
            for (int r = 0; r < 4; ++r)
                X2s[(lg*4 + r)*SX + o] = f2b(fmaxf(acc[ct][r] + bias, 0.f));
        }
    }
    __syncthreads();

    {   // phase 3: X3 = X2 @ Wx2^T + b (linear) -> global bf16 [p][256]
        f32x4 acc[4] = {z,z,z,z};
        #pragma unroll
        for (int ks = 0; ks < 8; ++ks) {
            s16x8 a = *(const s16x8*)&X2s[cl*SX + ks*32 + lg*8];
            #pragma unroll
            for (int ct = 0; ct < 4; ++ct) {
                int o = w*64 + ct*16 + cl;
                s16x8 b = *(const s16x8*)&Wx2b[(size_t)o*256 + ks*32 + lg*8];
                acc[ct] = MFMA(a, b, acc[ct]);
            }
        }
        #pragma unroll
        for (int ct = 0; ct < 4; ++ct) {
            int o = w*64 + ct*16 + cl;
            float bias = bx2[o];
            #pragma unroll
            for (int r = 0; r < 4; ++r)
                X3b[(size_t)(base + lg*4 + r)*256 + o] = f2b(acc[ct][r] + bias);
        }
    }
}

// ---------------- kB v4: barrier-free, wave-independent ----------------
// 4 points/block (4 waves); wave w owns point p = blockIdx*4+w and LDS rows
// w*16..w*16+15 exclusively -> NO __syncthreads anywhere.
#define SF 72
__global__ __launch_bounds__(256) void kB_mfma(
    const float* __restrict__ rep, const float* __restrict__ pts,
    const float* __restrict__ fts, const float* __restrict__ W1p,
    const unsigned short* __restrict__ Wf2b, const float* __restrict__ bf2,
    const float* __restrict__ Wdw, const float* __restrict__ bdw,
    const unsigned short* __restrict__ X3b, unsigned short* __restrict__ dwb)
{
    __shared__ __align__(16) unsigned short fcT[128*SF];  // [c][local row]
    const int tid = threadIdx.x;
    const int w = tid >> 6, lane = tid & 63, cl = lane & 15, lg = lane >> 4;
    const int p = blockIdx.x*4 + w;       // this wave's point
    const int rw = w*16;                  // wave-private local-row base

    // ---- issue global loads early ----
    const int frow = lane >> 2, fch = lane & 3;           // fts: 16 rows x 4 chunks
    float4 fv[4];
    #pragma unroll
    for (int it = 0; it < 4; ++it)
        fv[it] = *(const float4*)&fts[((size_t)p*16 + frow)*64 + fch*4 + it*16];

    s16x8 xa = {0,0,0,0,0,0,0,0};                         // X A-frag, K 16->32 pad
    if (lg < 2) xa = *(const s16x8*)&X3b[(size_t)p*256 + cl*16 + lg*8];

    const int row = p*16 + cl;                            // FC1 row for this lane
    float x0 = pts[(size_t)row*3+0] - rep[p*3+0];
    float x1 = pts[(size_t)row*3+1] - rep[p*3+1];
    float x2 = pts[(size_t)row*3+2] - rep[p*3+2];

    // ---- FC1 in registers: lane computes h[row][f] for exactly the f-octets
    // its FC2 B-frag needs (f = ks*32 + lg*8 + j) ----
    s16x8 hb[2];
    #pragma unroll
    for (int ks = 0; ks < 2; ++ks) {
        #pragma unroll
        for (int j = 0; j < 8; ++j) {
            int f = ks*32 + lg*8 + j;
            float4 wb4 = *(const float4*)&W1p[f*4];       // w0,w1,w2,bias
            float h = fmaxf(wb4.w + wb4.x*x0 + wb4.y*x1 + wb4.z*x2, 0.f);
            hb[ks][j] = (short)f2b(h);
        }
    }

    // ---- stage fts transposed into wave-private columns of fcT ----
    #pragma unroll
    for (int it = 0; it < 4; ++it) {
        float vv[4] = {fv[it].x, fv[it].y, fv[it].z, fv[it].w};
        #pragma unroll
        for (int cc = 0; cc < 4; ++cc) {
            int c = fch*4 + it*16 + cc;
            fcT[(64 + c)*SF + rw + frow] = f2b(vv[cc]);
        }
    }

    f32x4 z = {0.f,0.f,0.f,0.f};
    // ---- FC2 swapped MFMA: D[g][row_local] ----
    {
        f32x4 acc2[4] = {z,z,z,z};
        #pragma unroll
        for (int ks = 0; ks < 2; ++ks) {
            s16x8 b = hb[ks];
            #pragma unroll
            for (int gt = 0; gt < 4; ++gt) {
                s16x8 a = *(const s16x8*)&Wf2b[(gt*16 + cl)*64 + ks*32 + lg*8];
                acc2[gt] = MFMA(a, b, acc2[gt]);
            }
        }
        #pragma unroll
        for (int gt = 0; gt < 4; ++gt) {
            #pragma unroll
            for (int r = 0; r < 4; ++r) {
                int g = gt*16 + lg*4 + r;
                fcT[g*SF + rw + cl] = f2b(fmaxf(acc2[gt][r] + bf2[g], 0.f));
            }
        }
    }

    // ---- fts_X: fx[ct] = X_p @ fcat (wave-private rows; no barrier needed) ----
    f32x4 fx[8];
    #pragma unroll
    for (int ct = 0; ct < 8; ++ct) {
        int c = ct*16 + cl;
        s16x8 b = *(const s16x8*)&fcT[c*SF + rw + (lg & 1)*8];
        fx[ct] = MFMA(xa, b, z);
    }

    // ---- depthwise + bias -> dwb bf16 [p][512] ----
    #pragma unroll
    for (int ct = 0; ct < 8; ++ct) {
        int c = ct*16 + cl;
        float4 b4 = *(const float4*)&bdw[c*4];
        float om[4];
        #pragma unroll
        for (int m = 0; m < 4; ++m) {
            float4 wv = *(const float4*)&Wdw[(size_t)(c*4 + m)*16 + lg*4];
            float s = fx[ct][0]*wv.x + fx[ct][1]*wv.y + fx[ct][2]*wv.z + fx[ct][3]*wv.w;
            s += __shfl_xor(s, 16);
            s += __shfl_xor(s, 32);
            om[m] = s + ((const float*)&b4)[m];
        }
        if (lg == 0) {
            ushort4 pk; pk.x = f2b(om[0]); pk.y = f2b(om[1]); pk.z = f2b(om[2]); pk.w = f2b(om[3]);
            *(ushort4*)&dwb[(size_t)p*512 + c*4] = pk;
        }
    }
}

// ---------------- kC: pointwise MFMA GEMM (M=16384, N=128, K=512) ----------------
__global__ __launch_bounds__(256) void kC_mfma(
    const unsigned short* __restrict__ dwb, const unsigned short* __restrict__ Wpwb,
    const float* __restrict__ bpw, float* __restrict__ y)
{
    const int tid = threadIdx.x;
    const int w = tid >> 6, lane = tid & 63, cl = lane & 15, lg = lane >> 4;
    const int m0 = blockIdx.x*32 + (w & 1)*16;
    const int nh = w >> 1;
    f32x4 z = {0.f,0.f,0.f,0.f};
    f32x4 acc[4] = {z,z,z,z};
    for (int ks = 0; ks < 16; ++ks) {
        s16x8 a = *(const s16x8*)&dwb[(size_t)(m0 + cl)*512 + ks*32 + lg*8];
        #pragma unroll
        for (int ct = 0; ct < 4; ++ct) {
            int o = nh*64 + ct*16 + cl;
            s16x8 b = *(const s16x8*)&Wpwb[(size_t)o*512 + ks*32 + lg*8];
            acc[ct] = MFMA(a, b, acc[ct]);
        }
    }
    #pragma unroll
    for (int ct = 0; ct < 4; ++ct) {
        int o = nh*64 + ct*16 + cl;
        float bias = bpw[o];
        #pragma unroll
        for (int r = 0; r < 4; ++r)
            y[(size_t)(m0 + lg*4 + r)*128 + o] = acc[ct][r] + bias;
    }
}

// ---------------- kZ / kD1 / kD2 / kE: BN + relu ----------------
__global__ void kZ_zero(float* __restrict__ acc) { acc[threadIdx.x] = 0.f; }

__global__ __launch_bounds__(256) void kD1_part(
    const float* __restrict__ y, float* __restrict__ accS, float* __restrict__ accS2)
{
    __shared__ float sL[8][128], s2L[8][128];
    const int tid = threadIdx.x;
    const int rg = tid >> 5, clx = tid & 31;
    const int base = blockIdx.x * 64;
    float4 s = make_float4(0,0,0,0), s2 = make_float4(0,0,0,0);
    #pragma unroll
    for (int rr = 0; rr < 8; ++rr) {
        float4 v = *(const float4*)(y + (size_t)(base + rg*8 + rr)*128 + clx*4);
        s.x += v.x; s.y += v.y; s.z += v.z; s.w += v.w;
        s2.x += v.x*v.x; s2.y += v.y*v.y; s2.z += v.z*v.z; s2.w += v.w*v.w;
    }
    *(float4*)&sL[rg][clx*4] = s;
    *(float4*)&s2L[rg][clx*4] = s2;
    __syncthreads();
    if (tid < 128) {
        float a = 0.f, b = 0.f;
        #pragma unroll
        for (int g = 0; g < 8; ++g) { a += sL[g][tid]; b += s2L[g][tid]; }
        atomicAdd(accS + tid, a);
        atomicAdd(accS2 + tid, b);
    }
}

__global__ void kD2_fin(
    const float* __restrict__ accS, const float* __restrict__ accS2,
    const float* __restrict__ gamma, const float* __restrict__ beta,
    float* __restrict__ st)
{
    const int c = threadIdx.x;
    float mean = accS[c] * (1.f/NPTS);
    float var  = accS2[c] * (1.f/NPTS) - mean*mean;
    float rstd = rsqrtf(var + 1e-5f);
    float sc = gamma[c] * rstd;
    st[c] = sc;
    st[128 + c] = beta[c] - mean*sc;
}

__global__ __launch_bounds__(256) void kE_final(
    const float* __restrict__ y, const float* __restrict__ st,
    float* __restrict__ out)
{
    const int idx = blockIdx.x*256 + threadIdx.x;
    float4 v = ((const float4*)y)[idx];
    int o0 = (idx & 31) << 2;
    float4 sc = *(const float4*)(st + o0);
    float4 sh = *(const float4*)(st + 128 + o0);
    float4 r;
    r.x = fmaxf(v.x*sc.x + sh.x, 0.f);
    r.y = fmaxf(v.y*sc.y + sh.y, 0.f);
    r.z = fmaxf(v.z*sc.z + sh.z, 0.f);
    r.w = fmaxf(v.w*sc.w + sh.w, 0.f);
    ((float4*)out)[idx] = r;
}

extern "C" void kernel_launch(void* const* d_in, const int* in_sizes, int n_in,
                              void* d_out, int out_size, void* d_ws, size_t ws_size,
                              hipStream_t stream) {
    const float* rep  = (const float*)d_in[0];
    const float* pts  = (const float*)d_in[1];
    const float* fts  = (const float*)d_in[2];
    const float* Wf1  = (const float*)d_in[3];
    const float* bf1  = (const float*)d_in[4];
    const float* Wf2  = (const float*)d_in[5];
    const float* bf2  = (const float*)d_in[6];
    const float* Wxc  = (const float*)d_in[7];
    const float* bxc  = (const float*)d_in[8];
    const float* Wx1  = (const float*)d_in[9];
    const float* bx1  = (const float*)d_in[10];
    const float* Wx2  = (const float*)d_in[11];
    const float* bx2  = (const float*)d_in[12];
    const float* Wdw  = (const float*)d_in[13];
    const float* bdw  = (const float*)d_in[14];
    const float* Wpw  = (const float*)d_in[15];
    const float* bpw  = (const float*)d_in[16];
    const float* gam  = (const float*)d_in[17];
    const float* bet  = (const float*)d_in[18];

    unsigned short* X3b = (unsigned short*)d_ws;                 // 16384*256 bf16
    unsigned short* dwb = X3b + (size_t)NPTS*256;                // 16384*512 bf16
    float* y   = (float*)(dwb + (size_t)NPTS*512);               // 16384*128 f32
    float* st  = y + (size_t)NPTS*128;                           // 256
    float* acc = st + 256;                                       // 256
    unsigned short* Wb = (unsigned short*)(acc + 256);           // 217088 bf16
    unsigned short* Wxcb = Wb;
    unsigned short* Wx1b = Wxcb + 16384;
    unsigned short* Wx2b = Wx1b + 65536;
    unsigned short* Wf2b = Wx2b + 65536;
    unsigned short* Wpwb = Wf2b + 4096;
    float* W1p = (float*)(Wb + 217088);                          // 256 f32

    kZ_zero<<<1, 256, 0, stream>>>(acc);
    kW_cvt<<<850, 256, 0, stream>>>(Wxc, Wx1, Wx2, Wf2, Wpw, Wf1, bf1, Wb, W1p);
    kA_mfma<<<NPTS/16, 256, 0, stream>>>(rep, pts, Wxcb, bxc, Wx1b, bx1, Wx2b, bx2, X3b);
    kB_mfma<<<NPTS/4, 256, 0, stream>>>(rep, pts, fts, W1p, Wf2b, bf2, Wdw, bdw, X3b, dwb);
    kC_mfma<<<NPTS/32, 256, 0, stream>>>(dwb, Wpwb, bpw, y);
    kD1_part<<<NPTS/64, 256, 0, stream>>>(y, acc, acc + 128);
    kD2_fin<<<1, 128, 0, stream>>>(acc, acc + 128, gam, bet, st);
    kE_final<<<(NPTS*128/4)/256, 256, 0, stream>>>(y, st, (float*)d_out);
}

// Round 6
// 169.665 us; speedup vs baseline: 1.0957x; 1.0196x over previous
//
#include <hip/hip_runtime.h>

// XConv fused bf16-MFMA pipeline. N=16, P=1024, K=16, D=3, Cf=64, Fin=64,
// Ccat=128, DM=4, Cout=128. NPTS=16384 points, 262144 rows.
//
// MFMA conventions (mfma_f32_16x16x32_bf16, m89-verified):
//  A-frag: lane&15 = M-row, k = (lane>>4)*8 + [0..7]  ([M][K] row-major)
//  B-frag: lane&15 = N-col, k = (lane>>4)*8 + [0..7]  ([N][K] row-major)
//  D:      col(N) = lane&15, row(M) = (lane>>4)*4 + reg

#define NPTS 16384

typedef short  s16x8 __attribute__((ext_vector_type(8)));
typedef float  f32x4 __attribute__((ext_vector_type(4)));

__device__ inline unsigned short f2b(float f) {
    unsigned u = __builtin_bit_cast(unsigned, f);
    unsigned r = u + 0x7FFF + ((u >> 16) & 1);
    return (unsigned short)(r >> 16);
}

#define MFMA(a,b,c) __builtin_amdgcn_mfma_f32_16x16x32_bf16((a),(b),(c),0,0,0)

// ---------------- kW: weight prep ----------------
// bf16 B^T layouts + W1 pack (f32) + Wdw transpose Wt[m][c][k] (f32)
__global__ __launch_bounds__(256) void kW_cvt(
    const float* __restrict__ Wxc, const float* __restrict__ Wx1,
    const float* __restrict__ Wx2, const float* __restrict__ Wf2,
    const float* __restrict__ Wpw, const float* __restrict__ Wf1,
    const float* __restrict__ bf1, const float* __restrict__ Wdw,
    unsigned short* __restrict__ Wb, float* __restrict__ W1p,
    float* __restrict__ Wt)
{
    unsigned short* Wxcb = Wb;            // [256][64] (K 48->64 zero-pad)
    unsigned short* Wx1b = Wxcb + 16384;  // [256][256]
    unsigned short* Wx2b = Wx1b + 65536;  // [256][256]
    unsigned short* Wf2b = Wx2b + 65536;  // [64][64]
    unsigned short* Wpwb = Wf2b + 4096;   // [128][512]
    int idx = blockIdx.x * 256 + threadIdx.x;
    if (idx < 16384) { int o = idx >> 6, j = idx & 63;
        Wxcb[idx] = (j < 48) ? f2b(Wxc[o*48 + j]) : 0; return; }
    idx -= 16384;
    if (idx < 65536) { Wx1b[idx] = f2b(Wx1[idx]); return; }
    idx -= 65536;
    if (idx < 65536) { Wx2b[idx] = f2b(Wx2[idx]); return; }
    idx -= 65536;
    if (idx < 4096)  { Wf2b[idx] = f2b(Wf2[idx]); return; }
    idx -= 4096;
    if (idx < 65536) { Wpwb[idx] = f2b(Wpw[idx]); return; }
    idx -= 65536;
    if (idx < 256)   { int f = idx >> 2, j = idx & 3;
        W1p[idx] = (j < 3) ? Wf1[f*3 + j] : bf1[f]; return; }
    idx -= 256;
    if (idx < 8192)  { int m = idx >> 11, rem = idx & 2047;
        int c = rem >> 4, k = rem & 15;
        Wt[idx] = Wdw[(size_t)(c*4 + m)*16 + k]; return; }
}

// ---------------- kF: fused X-chain + lift + fts_X + dw + pw + stats ----------------
// 16 points/block, 1024 blocks, 256 thr = 4 waves.
// LDS overlay (shorts):
//   ph1-2: X1s[0..4224) X2s[4224..8448) pA[8448..9600)
//   ph3-4a: X3L[0..4096) (over X1s; X2s still live in ph3)
//   ph4-5: fcT[0..9216) dwL bytes [18432..34816)
#define SA 72     // pA stride
#define SX 264    // X1s/X2s stride
#define SF 72     // fcT stride
__global__ __launch_bounds__(256) void kF_fused(
    const float* __restrict__ rep, const float* __restrict__ pts,
    const float* __restrict__ fts,
    const unsigned short* __restrict__ Wxcb, const float* __restrict__ bxc,
    const unsigned short* __restrict__ Wx1b, const float* __restrict__ bx1,
    const unsigned short* __restrict__ Wx2b, const float* __restrict__ bx2,
    const float* __restrict__ W1p,
    const unsigned short* __restrict__ Wf2b, const float* __restrict__ bf2,
    const float* __restrict__ Wt, const float* __restrict__ bdw,
    const unsigned short* __restrict__ Wpwb, const float* __restrict__ bpw,
    float* __restrict__ y, float* __restrict__ accS, float* __restrict__ accS2)
{
    __shared__ __align__(16) unsigned short SM[17408];   // 34816 B
    unsigned short* X1s = SM;
    unsigned short* X2s = SM + 4224;
    unsigned short* pA  = SM + 8448;
    unsigned short* X3L = SM;            // ph3 output (over dead X1s)
    unsigned short* fcT = SM;            // ph4 (over dead X3L/X2s)
    char*           dwB = (char*)(SM + 9216);   // 16384 B

    const int tid = threadIdx.x;
    const int w = tid >> 6, lane = tid & 63, cl = lane & 15, lg = lane >> 4;
    const int base = blockIdx.x * 16;
    f32x4 z = {0.f,0.f,0.f,0.f};

    // ---- stage local coords ----
    for (int idx = tid; idx < 1024; idx += 256) {
        int pt = idx >> 6, j = idx & 63;
        float v = 0.f;
        if (j < 48) { int d = j >> 4, kk = j & 15;
            v = pts[(size_t)((base+pt)*16 + kk)*3 + d] - rep[(base+pt)*3 + d]; }
        pA[pt*SA + j] = f2b(v);
    }
    __syncthreads();

    {   // ---- ph1: X1 = relu(ptsl @ Wxc^T + b), K=64 ----
        f32x4 acc[4] = {z,z,z,z};
        #pragma unroll
        for (int ks = 0; ks < 2; ++ks) {
            s16x8 a = *(const s16x8*)&pA[cl*SA + ks*32 + lg*8];
            #pragma unroll
            for (int ct = 0; ct < 4; ++ct) {
                int o = w*64 + ct*16 + cl;
                s16x8 b = *(const s16x8*)&Wxcb[o*64 + ks*32 + lg*8];
                acc[ct] = MFMA(a, b, acc[ct]);
            }
        }
        #pragma unroll
        for (int ct = 0; ct < 4; ++ct) {
            int o = w*64 + ct*16 + cl;
            float bias = bxc[o];
            #pragma unroll
            for (int r = 0; r < 4; ++r)
                X1s[(lg*4 + r)*SX + o] = f2b(fmaxf(acc[ct][r] + bias, 0.f));
        }
    }
    __syncthreads();

    {   // ---- ph2: X2 = relu(X1 @ Wx1^T + b), K=256 ----
        f32x4 acc[4] = {z,z,z,z};
        #pragma unroll
        for (int ks = 0; ks < 8; ++ks) {
            s16x8 a = *(const s16x8*)&X1s[cl*SX + ks*32 + lg*8];
            #pragma unroll
            for (int ct = 0; ct < 4; ++ct) {
                int o = w*64 + ct*16 + cl;
                s16x8 b = *(const s16x8*)&Wx1b[(size_t)o*256 + ks*32 + lg*8];
                acc[ct] = MFMA(a, b, acc[ct]);
            }
        }
        #pragma unroll
        for (int ct = 0; ct < 4; ++ct) {
            int o = w*64 + ct*16 + cl;
            float bias = bx1[o];
            #pragma unroll
            for (int r = 0; r < 4; ++r)
                X2s[(lg*4 + r)*SX + o] = f2b(fmaxf(acc[ct][r] + bias, 0.f));
        }
    }
    __syncthreads();

    {   // ---- ph3: X3 = X2 @ Wx2^T + b -> X3L[pt][256] (over dead X1s) ----
        f32x4 acc[4] = {z,z,z,z};
        #pragma unroll
        for (int ks = 0; ks < 8; ++ks) {
            s16x8 a = *(const s16x8*)&X2s[cl*SX + ks*32 + lg*8];
            #pragma unroll
            for (int ct = 0; ct < 4; ++ct) {
                int o = w*64 + ct*16 + cl;
                s16x8 b = *(const s16x8*)&Wx2b[(size_t)o*256 + ks*32 + lg*8];
                acc[ct] = MFMA(a, b, acc[ct]);
            }
        }
        #pragma unroll
        for (int ct = 0; ct < 4; ++ct) {
            int o = w*64 + ct*16 + cl;
            float bias = bx2[o];
            #pragma unroll
            for (int r = 0; r < 4; ++r)
                X3L[(lg*4 + r)*256 + o] = f2b(acc[ct][r] + bias);
        }
    }
    __syncthreads();

    // ---- ph4a: grab all 4 X A-frags into regs, then free X3L ----
    s16x8 xa[4];
    #pragma unroll
    for (int j = 0; j < 4; ++j) {
        s16x8 v = {0,0,0,0,0,0,0,0};
        if (lg < 2) v = *(const s16x8*)&X3L[(w*4 + j)*256 + cl*16 + lg*8];
        xa[j] = v;
    }
    __syncthreads();

    // ---- ph4: per-wave loop over its 4 points (wave-private fcT rows) ----
    const int rw = w*16;
    const int frow = lane >> 2, fch = lane & 3;
    #pragma unroll
    for (int j = 0; j < 4; ++j) {
        const int pl = w*4 + j;
        const int pg = base + pl;

        // fts loads (early)
        float4 fv[4];
        #pragma unroll
        for (int it = 0; it < 4; ++it)
            fv[it] = *(const float4*)&fts[((size_t)pg*16 + frow)*64 + fch*4 + it*16];

        // FC1 in regs: exactly the f-octets this lane's FC2 B-frag needs
        const int row = pg*16 + cl;
        float x0 = pts[(size_t)row*3+0] - rep[pg*3+0];
        float x1 = pts[(size_t)row*3+1] - rep[pg*3+1];
        float x2 = pts[(size_t)row*3+2] - rep[pg*3+2];
        s16x8 hb[2];
        #pragma unroll
        for (int ks = 0; ks < 2; ++ks) {
            #pragma unroll
            for (int e = 0; e < 8; ++e) {
                int f = ks*32 + lg*8 + e;
                float4 wb4 = *(const float4*)&W1p[f*4];
                float h = fmaxf(wb4.w + wb4.x*x0 + wb4.y*x1 + wb4.z*x2, 0.f);
                hb[ks][e] = (short)f2b(h);
            }
        }

        // stage fts transposed -> fcT[64+c][rw+frow]
        #pragma unroll
        for (int it = 0; it < 4; ++it) {
            float vv[4] = {fv[it].x, fv[it].y, fv[it].z, fv[it].w};
            #pragma unroll
            for (int cc = 0; cc < 4; ++cc) {
                int c = fch*4 + it*16 + cc;
                fcT[(64 + c)*SF + rw + frow] = f2b(vv[cc]);
            }
        }

        // FC2 swapped MFMA: D[g][row] -> fcT[g][rw+cl]
        {
            f32x4 acc2[4] = {z,z,z,z};
            #pragma unroll
            for (int ks = 0; ks < 2; ++ks) {
                #pragma unroll
                for (int gt = 0; gt < 4; ++gt) {
                    s16x8 a = *(const s16x8*)&Wf2b[(gt*16 + cl)*64 + ks*32 + lg*8];
                    acc2[gt] = MFMA(a, hb[ks], acc2[gt]);
                }
            }
            #pragma unroll
            for (int gt = 0; gt < 4; ++gt) {
                #pragma unroll
                for (int r = 0; r < 4; ++r) {
                    int g = gt*16 + lg*4 + r;
                    fcT[g*SF + rw + cl] = f2b(fmaxf(acc2[gt][r] + bf2[g], 0.f));
                }
            }
        }

        // fts_X: fx[ct] = X_p @ fcat (wave-private rows, in-order DS pipe)
        f32x4 fx[8];
        #pragma unroll
        for (int ct = 0; ct < 8; ++ct) {
            int c = ct*16 + cl;
            s16x8 b = *(const s16x8*)&fcT[c*SF + rw + (lg & 1)*8];
            fx[ct] = MFMA(xa[j], b, z);
        }

        // depthwise (Wt[m][c][k] coalesced) + bias -> dwL swizzled
        #pragma unroll
        for (int ct = 0; ct < 8; ++ct) {
            int c = ct*16 + cl;
            float4 b4 = *(const float4*)&bdw[c*4];
            float om[4];
            #pragma unroll
            for (int m = 0; m < 4; ++m) {
                float4 wv = *(const float4*)&Wt[((m*128 + c)<<4) + lg*4];
                float s = fx[ct][0]*wv.x + fx[ct][1]*wv.y + fx[ct][2]*wv.z + fx[ct][3]*wv.w;
                s += __shfl_xor(s, 16);
                s += __shfl_xor(s, 32);
                om[m] = s + ((const float*)&b4)[m];
            }
            if (lg == 0) {
                ushort4 pk; pk.x=f2b(om[0]); pk.y=f2b(om[1]); pk.z=f2b(om[2]); pk.w=f2b(om[3]);
                int g = ((c >> 1) ^ (pl*4)) & 63;
                *(ushort4*)(dwB + pl*1024 + g*16 + (c & 1)*8) = pk;
            }
        }
    }
    __syncthreads();

    // ---- ph5: pointwise GEMM (M=16 pts, N=32/wave, K=512) + y + stats ----
    {
        f32x4 acc2[2] = {z,z};
        #pragma unroll 4
        for (int ks = 0; ks < 16; ++ks) {
            int g = ((ks*4 + lg) ^ (cl*4)) & 63;
            s16x8 a = *(const s16x8*)(dwB + cl*1024 + g*16);
            #pragma unroll
            for (int ct = 0; ct < 2; ++ct) {
                int o = w*32 + ct*16 + cl;
                s16x8 b = *(const s16x8*)&Wpwb[(size_t)o*512 + ks*32 + lg*8];
                acc2[ct] = MFMA(a, b, acc2[ct]);
            }
        }
        #pragma unroll
        for (int ct = 0; ct < 2; ++ct) {
            int o = w*32 + ct*16 + cl;
            float bias = bpw[o];
            float s1 = 0.f, s2 = 0.f;
            #pragma unroll
            for (int r = 0; r < 4; ++r) {
                float v = acc2[ct][r] + bias;
                y[(size_t)(base + lg*4 + r)*128 + o] = v;
                s1 += v; s2 += v*v;
            }
            s1 += __shfl_xor(s1, 16); s2 += __shfl_xor(s2, 16);
            s1 += __shfl_xor(s1, 32); s2 += __shfl_xor(s2, 32);
            if (lg == 0) {
                atomicAdd(accS + o, s1);
                atomicAdd(accS2 + o, s2);
            }
        }
    }
}

// ---------------- kZ / kD2 / kE ----------------
__global__ void kZ_zero(float* __restrict__ acc) { acc[threadIdx.x] = 0.f; }

__global__ void kD2_fin(
    const float* __restrict__ accS, const float* __restrict__ accS2,
    const float* __restrict__ gamma, const float* __restrict__ beta,
    float* __restrict__ st)
{
    const int c = threadIdx.x;
    float mean = accS[c] * (1.f/NPTS);
    float var  = accS2[c] * (1.f/NPTS) - mean*mean;
    float rstd = rsqrtf(var + 1e-5f);
    float sc = gamma[c] * rstd;
    st[c] = sc;
    st[128 + c] = beta[c] - mean*sc;
}

__global__ __launch_bounds__(256) void kE_final(
    const float* __restrict__ y, const float* __restrict__ st,
    float* __restrict__ out)
{
    const int idx = blockIdx.x*256 + threadIdx.x;
    float4 v = ((const float4*)y)[idx];
    int o0 = (idx & 31) << 2;
    float4 sc = *(const float4*)(st + o0);
    float4 sh = *(const float4*)(st + 128 + o0);
    float4 r;
    r.x = fmaxf(v.x*sc.x + sh.x, 0.f);
    r.y = fmaxf(v.y*sc.y + sh.y, 0.f);
    r.z = fmaxf(v.z*sc.z + sh.z, 0.f);
    r.w = fmaxf(v.w*sc.w + sh.w, 0.f);
    ((float4*)out)[idx] = r;
}

extern "C" void kernel_launch(void* const* d_in, const int* in_sizes, int n_in,
                              void* d_out, int out_size, void* d_ws, size_t ws_size,
                              hipStream_t stream) {
    const float* rep  = (const float*)d_in[0];
    const float* pts  = (const float*)d_in[1];
    const float* fts  = (const float*)d_in[2];
    const float* Wf1  = (const float*)d_in[3];
    const float* bf1  = (const float*)d_in[4];
    const float* Wf2  = (const float*)d_in[5];
    const float* bf2  = (const float*)d_in[6];
    const float* Wxc  = (const float*)d_in[7];
    const float* bxc  = (const float*)d_in[8];
    const float* Wx1  = (const float*)d_in[9];
    const float* bx1  = (const float*)d_in[10];
    const float* Wx2  = (const float*)d_in[11];
    const float* bx2  = (const float*)d_in[12];
    const float* Wdw  = (const float*)d_in[13];
    const float* bdw  = (const float*)d_in[14];
    const float* Wpw  = (const float*)d_in[15];
    const float* bpw  = (const float*)d_in[16];
    const float* gam  = (const float*)d_in[17];
    const float* bet  = (const float*)d_in[18];

    float* y   = (float*)d_ws;                         // 16384*128 f32
    float* st  = y + (size_t)NPTS*128;                 // 256
    float* acc = st + 256;                             // 256 (accS|accS2)
    unsigned short* Wb = (unsigned short*)(acc + 256); // 217088 bf16
    unsigned short* Wxcb = Wb;
    unsigned short* Wx1b = Wxcb + 16384;
    unsigned short* Wx2b = Wx1b + 65536;
    unsigned short* Wf2b = Wx2b + 65536;
    unsigned short* Wpwb = Wf2b + 4096;
    float* W1p = (float*)(Wb + 217088);                // 256 f32
    float* Wt  = W1p + 256;                            // 8192 f32

    kZ_zero<<<1, 256, 0, stream>>>(acc);
    kW_cvt<<<882, 256, 0, stream>>>(Wxc, Wx1, Wx2, Wf2, Wpw, Wf1, bf1, Wdw, Wb, W1p, Wt);
    kF_fused<<<NPTS/16, 256, 0, stream>>>(rep, pts, fts,
        Wxcb, bxc, Wx1b, bx1, Wx2b, bx2,
        W1p, Wf2b, bf2, Wt, bdw, Wpwb, bpw,
        y, acc, acc + 128);
    kD2_fin<<<1, 128, 0, stream>>>(acc, acc + 128, gam, bet, st);
    kE_final<<<(NPTS*128/4)/256, 256, 0, stream>>>(y, st, (float*)d_out);
}

// Round 7
// 165.074 us; speedup vs baseline: 1.1262x; 1.0278x over previous
//
#include <hip/hip_runtime.h>

// XConv bf16-MFMA pipeline (de-fused, weight-stationary kB).
// N=16, P=1024, K=16, D=3, Cf=64, Fin=64, Ccat=128, DM=4, Cout=128.
//
// MFMA conventions (mfma_f32_16x16x32_bf16, m89-verified):
//  A-frag: lane&15 = M-row, k = (lane>>4)*8 + [0..7]  ([M][K] row-major)
//  B-frag: lane&15 = N-col, k = (lane>>4)*8 + [0..7]  ([N][K] row-major)
//  D:      col(N) = lane&15, row(M) = (lane>>4)*4 + reg

#define NPTS 16384

typedef short  s16x8 __attribute__((ext_vector_type(8)));
typedef float  f32x4 __attribute__((ext_vector_type(4)));

__device__ inline unsigned short f2b(float f) {
    unsigned u = __builtin_bit_cast(unsigned, f);
    unsigned r = u + 0x7FFF + ((u >> 16) & 1);
    return (unsigned short)(r >> 16);
}
__device__ inline float b2f(unsigned short b) {
    return __builtin_bit_cast(float, (unsigned)b << 16);
}

#define MFMA(a,b,c) __builtin_amdgcn_mfma_f32_16x16x32_bf16((a),(b),(c),0,0,0)

// ---------------- kW: weight prep ----------------
__global__ __launch_bounds__(256) void kW_cvt(
    const float* __restrict__ Wxc, const float* __restrict__ Wx1,
    const float* __restrict__ Wx2, const float* __restrict__ Wf2,
    const float* __restrict__ Wpw, const float* __restrict__ Wf1,
    const float* __restrict__ bf1, const float* __restrict__ Wdw,
    unsigned short* __restrict__ Wb, float* __restrict__ W1p,
    unsigned short* __restrict__ Wtb)
{
    unsigned short* Wxcb = Wb;            // [256][64] (K 48->64 zero-pad)
    unsigned short* Wx1b = Wxcb + 16384;  // [256][256]
    unsigned short* Wx2b = Wx1b + 65536;  // [256][256]
    unsigned short* Wf2b = Wx2b + 65536;  // [64][64]
    unsigned short* Wpwb = Wf2b + 4096;   // [128][512]
    int idx = blockIdx.x * 256 + threadIdx.x;
    if (idx < 16384) { int o = idx >> 6, j = idx & 63;
        Wxcb[idx] = (j < 48) ? f2b(Wxc[o*48 + j]) : 0; return; }
    idx -= 16384;
    if (idx < 65536) { Wx1b[idx] = f2b(Wx1[idx]); return; }
    idx -= 65536;
    if (idx < 65536) { Wx2b[idx] = f2b(Wx2[idx]); return; }
    idx -= 65536;
    if (idx < 4096)  { Wf2b[idx] = f2b(Wf2[idx]); return; }
    idx -= 4096;
    if (idx < 65536) { Wpwb[idx] = f2b(Wpw[idx]); return; }
    idx -= 65536;
    if (idx < 256)   { int f = idx >> 2, j = idx & 3;
        W1p[idx] = (j < 3) ? Wf1[f*3 + j] : bf1[f]; return; }
    idx -= 256;
    if (idx < 8192)  { int m = idx >> 11, rem = idx & 2047;   // Wtb[m][c][k]
        int c = rem >> 4, k = rem & 15;
        Wtb[idx] = f2b(Wdw[(size_t)(c*4 + m)*16 + k]); return; }
}

// ---------------- kA: X-chain as 3 chained MFMA GEMMs (R5, unchanged) ----------------
#define SA 72
#define SX 264
__global__ __launch_bounds__(256) void kA_mfma(
    const float* __restrict__ rep, const float* __restrict__ pts,
    const unsigned short* __restrict__ Wxcb, const float* __restrict__ bxc,
    const unsigned short* __restrict__ Wx1b, const float* __restrict__ bx1,
    const unsigned short* __restrict__ Wx2b, const float* __restrict__ bx2,
    unsigned short* __restrict__ X3b)
{
    __shared__ __align__(16) unsigned short pA[16*SA];
    __shared__ __align__(16) unsigned short X1s[16*SX];
    __shared__ __align__(16) unsigned short X2s[16*SX];
    const int tid = threadIdx.x;
    const int w = tid >> 6, lane = tid & 63, cl = lane & 15, lg = lane >> 4;
    const int base = blockIdx.x * 16;

    for (int idx = tid; idx < 1024; idx += 256) {
        int pt = idx >> 6, j = idx & 63;
        float v = 0.f;
        if (j < 48) { int d = j >> 4, kk = j & 15;
            v = pts[(size_t)((base+pt)*16 + kk)*3 + d] - rep[(base+pt)*3 + d]; }
        pA[pt*SA + j] = f2b(v);
    }
    __syncthreads();

    f32x4 z = {0.f,0.f,0.f,0.f};
    {   // ph1: X1 = relu(ptsl @ Wxc^T + b), K=64
        f32x4 acc[4] = {z,z,z,z};
        #pragma unroll
        for (int ks = 0; ks < 2; ++ks) {
            s16x8 a = *(const s16x8*)&pA[cl*SA + ks*32 + lg*8];
            #pragma unroll
            for (int ct = 0; ct < 4; ++ct) {
                int o = w*64 + ct*16 + cl;
                s16x8 b = *(const s16x8*)&Wxcb[o*64 + ks*32 + lg*8];
                acc[ct] = MFMA(a, b, acc[ct]);
            }
        }
        #pragma unroll
        for (int ct = 0; ct < 4; ++ct) {
            int o = w*64 + ct*16 + cl;
            float bias = bxc[o];
            #pragma unroll
            for (int r = 0; r < 4; ++r)
                X1s[(lg*4 + r)*SX + o] = f2b(fmaxf(acc[ct][r] + bias, 0.f));
        }
    }
    __syncthreads();

    {   // ph2: X2 = relu(X1 @ Wx1^T + b), K=256
        f32x4 acc[4] = {z,z,z,z};
        #pragma unroll
        for (int ks = 0; ks < 8; ++ks) {
            s16x8 a = *(const s16x8*)&X1s[cl*SX + ks*32 + lg*8];
            #pragma unroll
            for (int ct = 0; ct < 4; ++ct) {
                int o = w*64 + ct*16 + cl;
                s16x8 b = *(const s16x8*)&Wx1b[(size_t)o*256 + ks*32 + lg*8];
                acc[ct] = MFMA(a, b, acc[ct]);
            }
        }
        #pragma unroll
        for (int ct = 0; ct < 4; ++ct) {
            int o = w*64 + ct*16 + cl;
            float bias = bx1[o];
            #pragma unroll
            for (int r = 0; r < 4; ++r)
                X2s[(lg*4 + r)*SX + o] = f2b(fmaxf(acc[ct][r] + bias, 0.f));
        }
    }
    __syncthreads();

    {   // ph3: X3 = X2 @ Wx2^T + b -> global bf16 [p][256]
        f32x4 acc[4] = {z,z,z,z};
        #pragma unroll
        for (int ks = 0; ks < 8; ++ks) {
            s16x8 a = *(const s16x8*)&X2s[cl*SX + ks*32 + lg*8];
            #pragma unroll
            for (int ct = 0; ct < 4; ++ct) {
                int o = w*64 + ct*16 + cl;
                s16x8 b = *(const s16x8*)&Wx2b[(size_t)o*256 + ks*32 + lg*8];
                acc[ct] = MFMA(a, b, acc[ct]);
            }
        }
        #pragma unroll
        for (int ct = 0; ct < 4; ++ct) {
            int o = w*64 + ct*16 + cl;
            float bias = bx2[o];
            #pragma unroll
            for (int r = 0; r < 4; ++r)
                X3b[(size_t)(base + lg*4 + r)*256 + o] = f2b(acc[ct][r] + bias);
        }
    }
}

// ---------------- kB3: weight-stationary lift + fts_X + depthwise ----------------
// 16 points/block (1024 blocks), 4 waves; wave w loops its 4 points.
// Wt (depthwise weights) staged bf16 in LDS once per block.
#define SF 72
__global__ __launch_bounds__(256) void kB_mfma(
    const float* __restrict__ rep, const float* __restrict__ pts,
    const float* __restrict__ fts, const float* __restrict__ W1p,
    const unsigned short* __restrict__ Wf2b, const float* __restrict__ bf2,
    const unsigned short* __restrict__ Wtb, const float* __restrict__ bdw,
    const unsigned short* __restrict__ X3b, unsigned short* __restrict__ dwb)
{
    __shared__ __align__(16) unsigned short fcT[128*SF];  // 18432 B
    __shared__ __align__(16) unsigned short WtL[8192];    // 16384 B  [m][c][k]
    const int tid = threadIdx.x;
    const int w = tid >> 6, lane = tid & 63, cl = lane & 15, lg = lane >> 4;
    const int rw = w*16;
    const int frow = lane >> 2, fch = lane & 3;

    #pragma unroll
    for (int i = 0; i < 4; ++i)                           // stage Wt: 1024 x 16B
        ((s16x8*)WtL)[tid + i*256] = ((const s16x8*)Wtb)[tid + i*256];
    __syncthreads();

    f32x4 z = {0.f,0.f,0.f,0.f};
    #pragma unroll
    for (int j = 0; j < 4; ++j) {
        const int pg = blockIdx.x*16 + w*4 + j;

        // fts loads (early, HBM stream)
        float4 fv[4];
        #pragma unroll
        for (int it = 0; it < 4; ++it)
            fv[it] = *(const float4*)&fts[((size_t)pg*16 + frow)*64 + fch*4 + it*16];

        // X A-frag (K 16->32 zero-pad)
        s16x8 xa = {0,0,0,0,0,0,0,0};
        if (lg < 2) xa = *(const s16x8*)&X3b[(size_t)pg*256 + cl*16 + lg*8];

        // FC1 in regs (W1p L1-hot global): the f-octets this lane's B-frag needs
        const int row = pg*16 + cl;
        float x0 = pts[(size_t)row*3+0] - rep[pg*3+0];
        float x1 = pts[(size_t)row*3+1] - rep[pg*3+1];
        float x2 = pts[(size_t)row*3+2] - rep[pg*3+2];
        s16x8 hb[2];
        #pragma unroll
        for (int ks = 0; ks < 2; ++ks) {
            #pragma unroll
            for (int e = 0; e < 8; ++e) {
                int f = ks*32 + lg*8 + e;
                float4 wb4 = *(const float4*)&W1p[f*4];
                float h = fmaxf(wb4.w + wb4.x*x0 + wb4.y*x1 + wb4.z*x2, 0.f);
                hb[ks][e] = (short)f2b(h);
            }
        }

        // stage fts transposed -> fcT[64+c][rw+frow] (wave-private rows)
        #pragma unroll
        for (int it = 0; it < 4; ++it) {
            float vv[4] = {fv[it].x, fv[it].y, fv[it].z, fv[it].w};
            #pragma unroll
            for (int cc = 0; cc < 4; ++cc) {
                int c = fch*4 + it*16 + cc;
                fcT[(64 + c)*SF + rw + frow] = f2b(vv[cc]);
            }
        }

        // FC2 swapped MFMA: D[g][row] -> fcT[g][rw+cl]
        {
            f32x4 acc2[4] = {z,z,z,z};
            #pragma unroll
            for (int ks = 0; ks < 2; ++ks) {
                #pragma unroll
                for (int gt = 0; gt < 4; ++gt) {
                    s16x8 a = *(const s16x8*)&Wf2b[(gt*16 + cl)*64 + ks*32 + lg*8];
                    acc2[gt] = MFMA(a, hb[ks], acc2[gt]);
                }
            }
            #pragma unroll
            for (int gt = 0; gt < 4; ++gt) {
                #pragma unroll
                for (int r = 0; r < 4; ++r) {
                    int g = gt*16 + lg*4 + r;
                    fcT[g*SF + rw + cl] = f2b(fmaxf(acc2[gt][r] + bf2[g], 0.f));
                }
            }
        }

        // fts_X: fx[ct] = X_p @ fcat (wave-private rows, in-order DS pipe)
        f32x4 fx[8];
        #pragma unroll
        for (int ct = 0; ct < 8; ++ct) {
            int c = ct*16 + cl;
            s16x8 b = *(const s16x8*)&fcT[c*SF + rw + (lg & 1)*8];
            fx[ct] = MFMA(xa, b, z);
        }

        // depthwise from LDS weights + bias -> dwb bf16 [p][512]
        #pragma unroll
        for (int ct = 0; ct < 8; ++ct) {
            int c = ct*16 + cl;
            float4 b4 = *(const float4*)&bdw[c*4];
            float om[4];
            #pragma unroll
            for (int m = 0; m < 4; ++m) {
                ushort4 wu = *(const ushort4*)&WtL[m*2048 + c*16 + lg*4];
                float s = fx[ct][0]*b2f(wu.x) + fx[ct][1]*b2f(wu.y)
                        + fx[ct][2]*b2f(wu.z) + fx[ct][3]*b2f(wu.w);
                s += __shfl_xor(s, 16);
                s += __shfl_xor(s, 32);
                om[m] = s + ((const float*)&b4)[m];
            }
            if (lg == 0) {
                ushort4 pk; pk.x=f2b(om[0]); pk.y=f2b(om[1]); pk.z=f2b(om[2]); pk.w=f2b(om[3]);
                *(ushort4*)&dwb[(size_t)pg*512 + c*4] = pk;
            }
        }
    }
}

// ---------------- kC2: pointwise MFMA GEMM + fused BN partial stats ----------------
__global__ __launch_bounds__(256) void kC_mfma(
    const unsigned short* __restrict__ dwb, const unsigned short* __restrict__ Wpwb,
    const float* __restrict__ bpw, float* __restrict__ y,
    float* __restrict__ accS, float* __restrict__ accS2)
{
    const int tid = threadIdx.x;
    const int w = tid >> 6, lane = tid & 63, cl = lane & 15, lg = lane >> 4;
    const int m0 = blockIdx.x*32 + (w & 1)*16;
    const int nh = w >> 1;
    f32x4 z = {0.f,0.f,0.f,0.f};
    f32x4 acc[4] = {z,z,z,z};
    for (int ks = 0; ks < 16; ++ks) {
        s16x8 a = *(const s16x8*)&dwb[(size_t)(m0 + cl)*512 + ks*32 + lg*8];
        #pragma unroll
        for (int ct = 0; ct < 4; ++ct) {
            int o = nh*64 + ct*16 + cl;
            s16x8 b = *(const s16x8*)&Wpwb[(size_t)o*512 + ks*32 + lg*8];
            acc[ct] = MFMA(a, b, acc[ct]);
        }
    }
    #pragma unroll
    for (int ct = 0; ct < 4; ++ct) {
        int o = nh*64 + ct*16 + cl;
        float bias = bpw[o];
        float s1 = 0.f, s2 = 0.f;
        #pragma unroll
        for (int r = 0; r < 4; ++r) {
            float v = acc[ct][r] + bias;
            y[(size_t)(m0 + lg*4 + r)*128 + o] = v;
            s1 += v; s2 += v*v;
        }
        s1 += __shfl_xor(s1, 16); s2 += __shfl_xor(s2, 16);
        s1 += __shfl_xor(s1, 32); s2 += __shfl_xor(s2, 32);
        if (lg == 0) {
            atomicAdd(accS + o, s1);
            atomicAdd(accS2 + o, s2);
        }
    }
}

// ---------------- kZ / kD2 / kE ----------------
__global__ void kZ_zero(float* __restrict__ acc) { acc[threadIdx.x] = 0.f; }

__global__ void kD2_fin(
    const float* __restrict__ accS, const float* __restrict__ accS2,
    const float* __restrict__ gamma, const float* __restrict__ beta,
    float* __restrict__ st)
{
    const int c = threadIdx.x;
    float mean = accS[c] * (1.f/NPTS);
    float var  = accS2[c] * (1.f/NPTS) - mean*mean;
    float rstd = rsqrtf(var + 1e-5f);
    float sc = gamma[c] * rstd;
    st[c] = sc;
    st[128 + c] = beta[c] - mean*sc;
}

__global__ __launch_bounds__(256) void kE_final(
    const float* __restrict__ y, const float* __restrict__ st,
    float* __restrict__ out)
{
    const int idx = blockIdx.x*256 + threadIdx.x;
    float4 v = ((const float4*)y)[idx];
    int o0 = (idx & 31) << 2;
    float4 sc = *(const float4*)(st + o0);
    float4 sh = *(const float4*)(st + 128 + o0);
    float4 r;
    r.x = fmaxf(v.x*sc.x + sh.x, 0.f);
    r.y = fmaxf(v.y*sc.y + sh.y, 0.f);
    r.z = fmaxf(v.z*sc.z + sh.z, 0.f);
    r.w = fmaxf(v.w*sc.w + sh.w, 0.f);
    ((float4*)out)[idx] = r;
}

extern "C" void kernel_launch(void* const* d_in, const int* in_sizes, int n_in,
                              void* d_out, int out_size, void* d_ws, size_t ws_size,
                              hipStream_t stream) {
    const float* rep  = (const float*)d_in[0];
    const float* pts  = (const float*)d_in[1];
    const float* fts  = (const float*)d_in[2];
    const float* Wf1  = (const float*)d_in[3];
    const float* bf1  = (const float*)d_in[4];
    const float* Wf2  = (const float*)d_in[5];
    const float* bf2  = (const float*)d_in[6];
    const float* Wxc  = (const float*)d_in[7];
    const float* bxc  = (const float*)d_in[8];
    const float* Wx1  = (const float*)d_in[9];
    const float* bx1  = (const float*)d_in[10];
    const float* Wx2  = (const float*)d_in[11];
    const float* bx2  = (const float*)d_in[12];
    const float* Wdw  = (const float*)d_in[13];
    const float* bdw  = (const float*)d_in[14];
    const float* Wpw  = (const float*)d_in[15];
    const float* bpw  = (const float*)d_in[16];
    const float* gam  = (const float*)d_in[17];
    const float* bet  = (const float*)d_in[18];

    unsigned short* X3b = (unsigned short*)d_ws;                 // 16384*256 bf16
    unsigned short* dwb = X3b + (size_t)NPTS*256;                // 16384*512 bf16
    float* y   = (float*)(dwb + (size_t)NPTS*512);               // 16384*128 f32
    float* st  = y + (size_t)NPTS*128;                           // 256
    float* acc = st + 256;                                       // 256
    unsigned short* Wb = (unsigned short*)(acc + 256);           // 217088 bf16
    unsigned short* Wxcb = Wb;
    unsigned short* Wx1b = Wxcb + 16384;
    unsigned short* Wx2b = Wx1b + 65536;
    unsigned short* Wf2b = Wx2b + 65536;
    unsigned short* Wpwb = Wf2b + 4096;
    float* W1p = (float*)(Wb + 217088);                          // 256 f32
    unsigned short* Wtb = (unsigned short*)(W1p + 256);          // 8192 bf16

    kZ_zero<<<1, 256, 0, stream>>>(acc);
    kW_cvt<<<882, 256, 0, stream>>>(Wxc, Wx1, Wx2, Wf2, Wpw, Wf1, bf1, Wdw, Wb, W1p, Wtb);
    kA_mfma<<<NPTS/16, 256, 0, stream>>>(rep, pts, Wxcb, bxc, Wx1b, bx1, Wx2b, bx2, X3b);
    kB_mfma<<<NPTS/16, 256, 0, stream>>>(rep, pts, fts, W1p, Wf2b, bf2, Wtb, bdw, X3b, dwb);
    kC_mfma<<<NPTS/32, 256, 0, stream>>>(dwb, Wpwb, bpw, y, acc, acc + 128);
    kD2_fin<<<1, 128, 0, stream>>>(acc, acc + 128, gam, bet, st);
    kE_final<<<(NPTS*128/4)/256, 256, 0, stream>>>(y, st, (float*)d_out);
}